// Round 1
// baseline (342.357 us; speedup 1.0000x reference)
//
#include <hip/hip_runtime.h>
#include <math.h>

// Problem constants (from reference): B=256, S=128, E=1024
#define Bb 256
#define Ss 128
#define Ee 1024
#define BK 64
#define APAD 72   // 64 + 8 elements pad -> 144B row stride (16B-aligned, breaks bank aliasing)

typedef __bf16 bf16x8 __attribute__((ext_vector_type(8)));
typedef float f32x4 __attribute__((ext_vector_type(4)));

typedef __attribute__((address_space(3))) unsigned int lds_u32;
typedef __attribute__((address_space(1))) unsigned int glb_u32;

static __device__ __forceinline__ unsigned short f2bf(float f) {
    // round-to-nearest-even f32 -> bf16
    unsigned int u = __float_as_uint(f);
    u += 0x7FFFu + ((u >> 16) & 1u);
    return (unsigned short)(u >> 16);
}

// ---------------------------------------------------------------------------
// Kernel 1: convert W [E,E] f32 -> bf16 (2 MB in ws). 4 elems/thread.
__global__ void convW_kernel(const float* __restrict__ W, unsigned short* __restrict__ Wb) {
    int i = blockIdx.x * blockDim.x + threadIdx.x;      // 262144 threads
    float4 v = reinterpret_cast<const float4*>(W)[i];
    ushort4 o;
    o.x = f2bf(v.x); o.y = f2bf(v.y); o.z = f2bf(v.z); o.w = f2bf(v.w);
    reinterpret_cast<ushort4*>(Wb)[i] = o;
}

// ---------------------------------------------------------------------------
// Kernel 2: fused scores GEMM.
// Block (b, ft): computes partial scores for bag b over f-columns [ft*128, ft*128+128).
// Only the 16-aligned strip span covering [start,end) rows is computed.
// part[(b*8+ft)*128 + s] = sum_{f in tile} tanh(h[b,s,f]) * u[f]
__launch_bounds__(256)
__global__ void scores_gemm(const float* __restrict__ x,
                            const unsigned short* __restrict__ Wb,
                            const float* __restrict__ u,
                            const int* __restrict__ doc,
                            float* __restrict__ part) {
    __shared__ unsigned short As[8 * 16 * APAD];   // up to 128 rows x 64 cols (padded): 18432 B
    __shared__ unsigned short Bs[128 * BK];        // 128 f-rows x 64 e-cols: 16384 B
    __shared__ float s_red[4][128];                // per-wave partial scores

    const int b  = blockIdx.x;
    const int ft = blockIdx.y;
    const int start = doc[2 * b], end = doc[2 * b + 1];
    const int strip0 = start >> 4;
    const int ns = ((end + 15) >> 4) - strip0;     // 1..8 strips of 16 rows
    const int row0 = strip0 << 4;

    const int tid  = threadIdx.x;
    const int wave = tid >> 6;
    const int lane = tid & 63;
    const int quad = lane >> 4;
    const int l16  = lane & 15;

    const float* xbase = x + ((size_t)b * Ss + row0) * Ee;
    const unsigned short* wbase = Wb + (size_t)ft * 128 * Ee;

    f32x4 acc[8][2];
    #pragma unroll
    for (int i = 0; i < 8; ++i) {
        #pragma unroll
        for (int j = 0; j < 2; ++j) acc[i][j] = (f32x4){0.f, 0.f, 0.f, 0.f};
    }

    for (int k0 = 0; k0 < Ee; k0 += BK) {
        // --- stage A: ns*16 rows x 64 cols, f32 -> bf16 through VGPRs (padded LDS) ---
        for (int r = 0; r < ns; ++r) {
            int idx = (r << 10) | (tid << 2);          // element index in 64-col row-major tile
            int row = idx >> 6, col = idx & 63;
            float4 v = *reinterpret_cast<const float4*>(xbase + (size_t)row * Ee + (k0 + col));
            ushort4 o;
            o.x = f2bf(v.x); o.y = f2bf(v.y); o.z = f2bf(v.z); o.w = f2bf(v.w);
            *reinterpret_cast<ushort4*>(&As[row * APAD + col]) = o;
        }
        // --- stage B: 128 x 64 bf16 = 16 KB via global_load_lds width 16 ---
        #pragma unroll
        for (int r = 0; r < 4; ++r) {
            int chunk = (r << 8) | tid;                // 0..1023, 16B each
            int brow = chunk >> 3, c8 = chunk & 7;
            const unsigned short* src = wbase + (size_t)brow * Ee + k0 + (c8 << 3);
            __builtin_amdgcn_global_load_lds((const glb_u32*)src,
                                             (lds_u32*)&Bs[chunk << 3], 16, 0, 0);
        }
        __syncthreads();

        // --- MFMA: wave handles cols [wave*32, wave*32+32), all strips ---
        #pragma unroll
        for (int kk = 0; kk < BK; kk += 32) {
            bf16x8 bf0 = *reinterpret_cast<const bf16x8*>(&Bs[(wave * 32 + l16) * BK + kk + quad * 8]);
            bf16x8 bf1 = *reinterpret_cast<const bf16x8*>(&Bs[(wave * 32 + 16 + l16) * BK + kk + quad * 8]);
            #pragma unroll
            for (int st = 0; st < 8; ++st) {
                if (st < ns) {   // block-uniform branch
                    bf16x8 af = *reinterpret_cast<const bf16x8*>(&As[(st * 16 + l16) * APAD + kk + quad * 8]);
                    acc[st][0] = __builtin_amdgcn_mfma_f32_16x16x32_bf16(af, bf0, acc[st][0], 0, 0, 0);
                    acc[st][1] = __builtin_amdgcn_mfma_f32_16x16x32_bf16(af, bf1, acc[st][1], 0, 0, 0);
                }
            }
        }
        __syncthreads();
    }

    // --- epilogue: tanh, *u, reduce over the 128 f-columns ---
    // C/D layout (16x16x32): col = lane&15, row = quad*4 + reg   [m89/m91 verified]
    const float u0 = u[ft * 128 + wave * 32 + l16];
    const float u1 = u[ft * 128 + wave * 32 + 16 + l16];
    #pragma unroll
    for (int st = 0; st < 8; ++st) {
        if (st < ns) {
            float p[4];
            #pragma unroll
            for (int r = 0; r < 4; ++r)
                p[r] = tanhf(acc[st][0][r]) * u0 + tanhf(acc[st][1][r]) * u1;
            #pragma unroll
            for (int off = 8; off >= 1; off >>= 1) {
                #pragma unroll
                for (int r = 0; r < 4; ++r)
                    p[r] += __shfl_xor(p[r], off, 16);
            }
            if (l16 == 0) {
                #pragma unroll
                for (int r = 0; r < 4; ++r)
                    s_red[wave][st * 16 + quad * 4 + r] = p[r];
            }
        }
    }
    __syncthreads();
    if (tid < (ns << 4)) {
        float v = s_red[0][tid] + s_red[1][tid] + s_red[2][tid] + s_red[3][tid];
        part[((size_t)b * 8 + ft) * 128 + row0 + tid] = v;
    }
}

// ---------------------------------------------------------------------------
// Kernel 3: masked softmax per bag. Block = bag (128 threads, 2 waves).
__global__ void softmax_kernel(const float* __restrict__ part,
                               const int* __restrict__ doc,
                               float* __restrict__ attn,
                               float* __restrict__ keep) {
    int b = blockIdx.x, s = threadIdx.x;
    int start = doc[2 * b], end = doc[2 * b + 1];
    bool m = (s >= start) && (s < end);
    float sc = -INFINITY;
    if (m) {
        sc = 0.f;
        #pragma unroll
        for (int ft = 0; ft < 8; ++ft)
            sc += part[((size_t)b * 8 + ft) * 128 + s];
    }
    __shared__ float red[2];
    float v = sc;
    #pragma unroll
    for (int off = 32; off >= 1; off >>= 1)
        v = fmaxf(v, __shfl_xor(v, off, 64));
    if ((s & 63) == 0) red[s >> 6] = v;
    __syncthreads();
    float mx = fmaxf(red[0], red[1]);
    __syncthreads();
    float e = m ? expf(sc - mx) : 0.f;
    v = e;
    #pragma unroll
    for (int off = 32; off >= 1; off >>= 1)
        v += __shfl_xor(v, off, 64);
    if ((s & 63) == 0) red[s >> 6] = v;
    __syncthreads();
    float a = e / (red[0] + red[1]);
    attn[b * Ss + s] = a;
    if (b == Bb - 1) keep[s] = a;   // keep_attention, zeros outside mask
}

// ---------------------------------------------------------------------------
// Kernel 4: out[b,e] = sum_s attn[b,s] * x[b,s,e], fp32. Block = bag.
__global__ void out_kernel(const float* __restrict__ x,
                           const float* __restrict__ attn,
                           const int* __restrict__ doc,
                           float* __restrict__ out) {
    int b = blockIdx.x, t = threadIdx.x;   // 256 threads, float4 over e
    int start = doc[2 * b], end = doc[2 * b + 1];
    __shared__ float a_s[Ss];
    if (t < Ss) a_s[t] = attn[b * Ss + t];
    __syncthreads();
    const float4* xb = reinterpret_cast<const float4*>(x + (size_t)b * Ss * Ee);
    float4 accv = {0.f, 0.f, 0.f, 0.f};
    for (int s = start; s < end; ++s) {
        float a = a_s[s];
        float4 xv = xb[s * 256 + t];
        accv.x += a * xv.x; accv.y += a * xv.y;
        accv.z += a * xv.z; accv.w += a * xv.w;
    }
    reinterpret_cast<float4*>(out)[b * 256 + t] = accv;
}

// ---------------------------------------------------------------------------
extern "C" void kernel_launch(void* const* d_in, const int* in_sizes, int n_in,
                              void* d_out, int out_size, void* d_ws, size_t ws_size,
                              hipStream_t stream) {
    const float* x  = (const float*)d_in[0];   // [B,S,E] f32
    const float* W  = (const float*)d_in[1];   // [E,E]   f32
    const float* u  = (const float*)d_in[2];   // [1,E]   f32
    const int* doc  = (const int*)d_in[3];     // [B,2]   i32
    float* out = (float*)d_out;                // [B*E] out_concat ++ [S] keep_attention

    // ws layout: Wb (2 MB) | part (1 MB) | attn (128 KB)  -> 3.25 MB total
    unsigned short* Wb = (unsigned short*)d_ws;
    float* part = (float*)((char*)d_ws + (size_t)Ee * Ee * 2);
    float* attn = (float*)((char*)d_ws + (size_t)Ee * Ee * 2 + (size_t)Bb * 8 * Ss * 4);

    convW_kernel<<<1024, 256, 0, stream>>>(W, Wb);
    scores_gemm<<<dim3(Bb, 8), 256, 0, stream>>>(x, Wb, u, doc, part);
    softmax_kernel<<<Bb, 128, 0, stream>>>(part, doc, attn, out + (size_t)Bb * Ee);
    out_kernel<<<Bb, 256, 0, stream>>>(x, attn, doc, out);
}